// Round 10
// baseline (1664.570 us; speedup 1.0000x reference)
//
#include <hip/hip_runtime.h>
#include <math.h>

#define NG 4096
#define M 50
#define KTOP 30
#define H 32
#define F_IN 128
#define EPG 400          // edges per graph (M * DEG)
#define PADE 552         // EPG + M*3: CSR rows padded to multiples of 4
#define E_TOTAL (NG * EPG)
#define DLAT 97
#define LATS 100         // padded stride for lat tile (keeps 16B alignment)
#define NTHREADS 256
#define WS_C1P 0         // ws: C1w padded [16][100], rows 16B-aligned

// fast tanh: 1 - 2/(e^{2x}+1). abs err ~1e-6; layers 1-3 only (layer 4 =
// sort key uses exact tanhf).
__device__ __forceinline__ float fast_tanh(float x) {
    x = fminf(fmaxf(x, -15.f), 15.f);
    float e = __expf(2.f * x);
    return 1.f - 2.f / (e + 1.f);
}

// ---- prep: pad C1w rows 97 -> 100 floats (16B-aligned rows, pad = 0) ----
__global__ void prep_kernel(const float* __restrict__ C1w, float* __restrict__ ws) {
    const int tid = blockIdx.x * blockDim.x + threadIdx.x;
    if (tid < 1600) {
        int c = tid / 100, d = tid - c * 100;
        ws[WS_C1P + tid] = (d < DLAT) ? C1w[c * DLAT + d] : 0.f;
    }
}

// -------- GCN matmul (LDS rows, coalesced W, FULLY unrolled k-loop) -------
// tbuf[i][j] = sum_k hin[i*istride+k] * W[k*H+j]
// thread (iset = tid>>5, j = tid&31) owns rows {iset, iset+8, ..., iset+48};
// row 49 recomputed by 6 threads (clamp) -- branch-free body.
// W loads per-lane consecutive (W[k*32+j]) -> coalesced 2 lines/wave
// (r6/r7 lesson: per-lane transposed rows = 32-line gather, +70us stall).
// FULL unroll: every ds_read/W-load gets an immediate offset from a fixed
// base reg -- no per-iteration address VALU (r9's unroll-2 kept dynamic
// address increments, ~230 extra VALU/wave in matmul-1).
template <int KIN>
__device__ __forceinline__ void gcn_matmul(const float* hin, int istride,
                                           const float* __restrict__ W,
                                           float (*tb)[H], int tid) {
    const int j = tid & 31, iset = tid >> 5;
    float acc[7];
    const float* base[7];
#pragma unroll
    for (int r = 0; r < 7; r++) {
        acc[r] = 0.f;
        int i = iset + r * 8;
        base[r] = hin + ((i >= M) ? (M - 1) : i) * istride;
    }
    const float* wbase = W + j;
#pragma unroll
    for (int k4 = 0; k4 < KIN / 4; k4++) {
        const float w0 = wbase[(4 * k4 + 0) * H];
        const float w1 = wbase[(4 * k4 + 1) * H];
        const float w2 = wbase[(4 * k4 + 2) * H];
        const float w3 = wbase[(4 * k4 + 3) * H];
#pragma unroll
        for (int r = 0; r < 7; r++) {
            const float4 xv = *(const float4*)(base[r] + 4 * k4);
            acc[r] += xv.x * w0 + xv.y * w1 + xv.z * w2 + xv.w * w3;
        }
    }
#pragma unroll
    for (int r = 0; r < 7; r++) {
        int i = iset + r * 8;
        if (i < M) tb[i][j] = acc[r];
    }
}

// aggregation + bias + tanh. Padded CSR: row extents are multiples of 4; one
// u32 load gives 4 packed u8 src ids, one b128 gives 4 norms, then 4
// INDEPENDENT tbuf reads -- 4x shorter dependent-LDS chain than scalar form.
__device__ __forceinline__ void gcn_agg(const float (*tbuf)[H], const float* __restrict__ b,
                                        float (*lat)[LATS], int col0,
                                        const float* dinv, const unsigned short* csr_off,
                                        const unsigned char* csr_src, const float* csr_nrm,
                                        int tid) {
    const int j = tid & 31, iset = tid >> 5;
    for (int i = iset; i < M; i += 8) {
        float acc = tbuf[i][j] * dinv[i] * dinv[i];   // self loop: norm = 1/deg
        int e0 = csr_off[i], e1 = csr_off[i + 1];
        for (int e = e0; e < e1; e += 4) {
            unsigned sp = *(const unsigned*)(csr_src + e);
            float4 nr = *(const float4*)(csr_nrm + e);
            acc += tbuf[sp & 255][j] * nr.x;
            acc += tbuf[(sp >> 8) & 255][j] * nr.y;
            acc += tbuf[(sp >> 16) & 255][j] * nr.z;
            acc += tbuf[sp >> 24][j] * nr.w;
        }
        lat[i][col0 + j] = fast_tanh(acc + b[j]);
    }
}

struct Post {                                      // 3392 B tail (phase union)
    float pbuf[16][15];
    union {
        struct { float z1[16][KTOP]; unsigned char ord[52]; } a;
        struct { float z2[352]; float red[256]; } b;
    } u;
};

// (256,4): spill-free point (64 VGPR, r2/r5/r8/r9). (256,5) clamps to 48
// VGPR + 70 MB scratch spill (r3); (256,3) changes nothing (r8).
__global__ __launch_bounds__(NTHREADS, 4)
void dgcnn_kernel(const float* __restrict__ x, const int* __restrict__ eidx,
                  const float* __restrict__ ws,
                  const float* __restrict__ W0, const float* __restrict__ b0,
                  const float* __restrict__ W1, const float* __restrict__ b1,
                  const float* __restrict__ W2, const float* __restrict__ b2,
                  const float* __restrict__ W3, const float* __restrict__ b3,
                  const float* __restrict__ C1b,
                  const float* __restrict__ C2w, const float* __restrict__ C2b,
                  const float* __restrict__ L1w, const float* __restrict__ L1b,
                  const float* __restrict__ L2w, const float* __restrict__ L2b,
                  float* __restrict__ out) {
    // xs (25600 B) is live only [stage .. layer-1 matmul]; lat+post born
    // after -> union. Total LDS 35264 B -> 4 blocks/CU (matches measured
    // occupancy of r5/r8/r9, so the union costs nothing).
    __shared__ __align__(16) union Big {
        float xs[M][F_IN];                 // 25600 B, dies after matmul-1
        struct { float lat[M][LATS]; Post post; } s;   // 23392 B
    } big;
    __shared__ __align__(16) float tbuf[M][H];     //  6400 B
    __shared__ __align__(16) float csr_nrm[PADE];  //  2208 B
    __shared__ unsigned char csr_src[PADE];        //   552 B
    __shared__ unsigned short csr_off[M + 2];      //   104 B
    __shared__ int   degi[M];                      //   200 B (becomes cursor)
    __shared__ float dinv[M];                      //   200 B

    const int g = blockIdx.x;
    const int tid = threadIdx.x;
    const int nbase = g * M;
    const int ebase = g * EPG;

    // ---- stage x tile -> LDS (coalesced float4); layer-1 then runs from
    // LDS broadcast instead of HBM-latency loads (r9: -41us).
    {
        const float4* xg4 = (const float4*)(x + (size_t)nbase * F_IN);
        float4* xs4 = (float4*)big.xs;
        for (int idx = tid; idx < M * F_IN / 4; idx += NTHREADS)
            xs4[idx] = xg4[idx];
    }
    // ---- init: degrees + zero padded CSR ----
    if (tid < M) degi[tid] = 1;
    for (int idx = tid; idx < PADE; idx += NTHREADS) {
        csr_nrm[idx] = 0.f;
        csr_src[idx] = 0;
    }
    __syncthreads();
    for (int e = tid; e < EPG; e += NTHREADS) {
        int d = eidx[E_TOTAL + ebase + e] - nbase;
        atomicAdd(&degi[d], 1);
    }
    __syncthreads();
    // ---- dinv + padded-CSR offsets (wave-0 shuffle scan); cursor=degi ----
    if (tid < M) dinv[tid] = rsqrtf((float)degi[tid]);
    if (tid < 64) {
        int cnt  = (tid < M) ? (degi[tid] - 1) : 0;
        int cntp = (cnt + 3) & ~3;
        int incl = cntp;
#pragma unroll
        for (int off = 1; off < 64; off <<= 1) {
            int nv = __shfl_up(incl, off);
            if (tid >= off) incl += nv;
        }
        if (tid < M) {
            csr_off[tid] = (unsigned short)(incl - cntp);
            degi[tid] = incl - cntp;
        }
        if (tid == M - 1) csr_off[M] = (unsigned short)incl;
    }
    __syncthreads();
    // ---- CSR fill + layer-1 matmul (independent; one barrier for both) ----
    for (int e = tid; e < EPG; e += NTHREADS) {
        int s = eidx[ebase + e] - nbase;
        int d = eidx[E_TOTAL + ebase + e] - nbase;
        float nr = dinv[s] * dinv[d];
        int pos = atomicAdd(&degi[d], 1);
        csr_src[pos] = (unsigned char)s;
        csr_nrm[pos] = nr;
    }
    gcn_matmul<F_IN>(&big.xs[0][0], F_IN, W0, tbuf, tid);
    __syncthreads();                     // xs dead from here; lat/post live

    // ---- layer 1 agg -> lat[:,0:32]; also zero lat pad cols 97..99 ----
    gcn_agg(tbuf, b0, big.s.lat, 0, dinv, csr_off, csr_src, csr_nrm, tid);
    for (int idx = tid; idx < 3 * M; idx += NTHREADS)
        big.s.lat[idx / 3][DLAT + idx % 3] = 0.f;   // conv1 reads 100 cols
    __syncthreads();
    // ---- layer 2 ----
    gcn_matmul<H>(&big.s.lat[0][0], LATS, W1, tbuf, tid);
    __syncthreads();
    gcn_agg(tbuf, b1, big.s.lat, 32, dinv, csr_off, csr_src, csr_nrm, tid);
    __syncthreads();
    // ---- layer 3 ----
    gcn_matmul<H>(&big.s.lat[0][32], LATS, W2, tbuf, tid);
    __syncthreads();
    gcn_agg(tbuf, b2, big.s.lat, 64, dinv, csr_off, csr_src, csr_nrm, tid);
    __syncthreads();
    // ---- layer 4 (H -> 1): exact tanhf (sort key) ----
    if (tid < M) {
        float acc = 0.f;
        for (int k = 0; k < H; k++) acc += big.s.lat[tid][64 + k] * W3[k];
        tbuf[tid][0] = acc;
    }
    __syncthreads();
    if (tid < M) {
        float acc = tbuf[tid][0] * dinv[tid] * dinv[tid];
        int e0 = csr_off[tid], e1 = csr_off[tid + 1];
        for (int e = e0; e < e1; e += 4) {
            unsigned sp = *(const unsigned*)(csr_src + e);
            float4 nr = *(const float4*)(csr_nrm + e);
            acc += tbuf[sp & 255][0] * nr.x + tbuf[(sp >> 8) & 255][0] * nr.y
                 + tbuf[(sp >> 16) & 255][0] * nr.z + tbuf[sp >> 24][0] * nr.w;
        }
        big.s.lat[tid][96] = tanhf(acc + b3[0]);
    }
    __syncthreads();

    // ---- sort-pool: stable descending rank over lat[:,96] ----
    if (tid < M) {
        float v = big.s.lat[tid][96];
        int r = 0;
        for (int jj = 0; jj < M; jj++) {
            float vj = big.s.lat[jj][96];
            r += (vj > v) || (vj == v && jj < tid);
        }
        big.s.post.u.a.ord[r] = (unsigned char)tid;
    }
    __syncthreads();

    // ---- Conv1d(1,16,97,stride 97) + ReLU, float4 over d ----
    // t=idx>>4: 16 lanes share a row -> LDS b128 broadcast; C1P rows (ws)
    // are 100 floats = 400 B (16B-aligned), pad cols = 0.
    for (int idx = tid; idx < 16 * KTOP; idx += NTHREADS) {
        int t = idx >> 4, c = idx & 15;
        const float4* row = (const float4*)big.s.lat[big.s.post.u.a.ord[t]];
        const float4* cw  = (const float4*)(ws + WS_C1P + c * LATS);
        float acc = 0.f;
#pragma unroll 5
        for (int q = 0; q < LATS / 4; q++) {
            float4 rv = row[q], wv = cw[q];
            acc += rv.x * wv.x + rv.y * wv.y + rv.z * wv.z + rv.w * wv.w;
        }
        big.s.post.u.a.z1[c][t] = fmaxf(acc + C1b[c], 0.f);
    }
    __syncthreads();

    // ---- MaxPool1d(2,2) -> pbuf (outside inner union) ----
    for (int idx = tid; idx < 16 * 15; idx += NTHREADS) {
        int c = idx / 15, t = idx - c * 15;
        big.s.post.pbuf[c][t] = fmaxf(big.s.post.u.a.z1[c][2 * t],
                                      big.s.post.u.a.z1[c][2 * t + 1]);
    }
    __syncthreads();

    // ---- Conv1d(16,32,5) + ReLU, flatten f = o*11 + t ----
    for (int idx = tid; idx < 352; idx += NTHREADS) {
        int o = idx / 11, t = idx - o * 11;
        float acc = C2b[o];
        for (int i = 0; i < 16; i++) {
#pragma unroll
            for (int k = 0; k < 5; k++)
                acc += big.s.post.pbuf[i][t + k] * C2w[(o * 16 + i) * 5 + k];
        }
        big.s.post.u.b.z2[idx] = fmaxf(acc, 0.f);
    }
    __syncthreads();

    // ---- Dense 352 -> 128 + ReLU (split over 2 halves; coalesced L1w) ----
    {
        int jj = tid & 127, half = tid >> 7;
        float acc = (half == 0) ? L1b[jj] : 0.f;
        int f0 = half * 176;
        for (int f = f0; f < f0 + 176; f++)
            acc += big.s.post.u.b.z2[f] * L1w[f * 128 + jj];
        big.s.post.u.b.red[tid] = acc;
    }
    __syncthreads();
    // ---- fuse ReLU + Dense 128 -> 1 ----
    if (tid < 128)
        big.s.post.u.b.red[tid] =
            fmaxf(big.s.post.u.b.red[tid] + big.s.post.u.b.red[tid + 128], 0.f)
            * L2w[tid];
    __syncthreads();
    if (tid < 64) {
        float v = big.s.post.u.b.red[tid] + big.s.post.u.b.red[tid + 64];
#pragma unroll
        for (int off = 32; off >= 1; off >>= 1)
            v += __shfl_down(v, off);
        if (tid == 0) out[g] = v + L2b[0];
    }
}

extern "C" void kernel_launch(void* const* d_in, const int* in_sizes, int n_in,
                              void* d_out, int out_size, void* d_ws, size_t ws_size,
                              hipStream_t stream) {
    const float* x    = (const float*)d_in[0];
    const int*   eidx = (const int*)d_in[1];
    // d_in[2] (batch) unused: graphs are contiguous equal-size blocks
    float* ws = (float*)d_ws;
    prep_kernel<<<7, 256, 0, stream>>>((const float*)d_in[11], ws);
    dgcnn_kernel<<<NG, NTHREADS, 0, stream>>>(
        x, eidx, ws,
        (const float*)d_in[3],  (const float*)d_in[4],
        (const float*)d_in[5],  (const float*)d_in[6],
        (const float*)d_in[7],  (const float*)d_in[8],
        (const float*)d_in[9],  (const float*)d_in[10],
        (const float*)d_in[12],
        (const float*)d_in[13], (const float*)d_in[14],
        (const float*)d_in[15], (const float*)d_in[16],
        (const float*)d_in[17], (const float*)d_in[18],
        (float*)d_out);
}

// Round 11
// 376.426 us; speedup vs baseline: 4.4220x; 4.4220x over previous
//
#include <hip/hip_runtime.h>
#include <math.h>

#define NG 4096
#define M 50
#define KTOP 30
#define H 32
#define F_IN 128
#define EPG 400          // edges per graph (M * DEG)
#define PADE 552         // EPG + M*3: CSR rows padded to multiples of 4
#define E_TOTAL (NG * EPG)
#define DLAT 97
#define LATS 100         // padded stride for lat tile (keeps 16B alignment)
#define NTHREADS 256
#define WS_C1P 0         // ws: C1w padded [16][100], rows 16B-aligned

// fast tanh: 1 - 2/(e^{2x}+1). abs err ~1e-6; layers 1-3 only (layer 4 =
// sort key uses exact tanhf).
__device__ __forceinline__ float fast_tanh(float x) {
    x = fminf(fmaxf(x, -15.f), 15.f);
    float e = __expf(2.f * x);
    return 1.f - 2.f / (e + 1.f);
}

// ---- prep: pad C1w rows 97 -> 100 floats (16B-aligned rows, pad = 0) ----
__global__ void prep_kernel(const float* __restrict__ C1w, float* __restrict__ ws) {
    const int tid = blockIdx.x * blockDim.x + threadIdx.x;
    if (tid < 1600) {
        int c = tid / 100, d = tid - c * 100;
        ws[WS_C1P + tid] = (d < DLAT) ? C1w[c * DLAT + d] : 0.f;
    }
}

// -------- GCN matmul (LDS rows, coalesced W, unroll-2) --------------------
// tbuf[i][j] = sum_k hin[i*istride+k] * W[k*H+j]
// thread (iset = tid>>5, j = tid&31) owns rows {iset, iset+8, ..., iset+48};
// row 49 recomputed by 6 threads (clamp) -- branch-free body.
// W loads per-lane consecutive (W[k*32+j]) -> coalesced 2 lines/wave
// (r6/r7 lesson: per-lane transposed rows = 32-line gather, +70us stall).
// UNROLL 2 EXACTLY: full unroll (r10) spilled ~550KB/block scratch
// (WRITE_SIZE 0.13MB -> 2.25GB, dur 265 -> 1550us). The compiler's spill-free
// schedule for this body exists only at unroll<=2 under the 64-VGPR budget.
template <int KIN>
__device__ __forceinline__ void gcn_matmul(const float* hin, int istride,
                                           const float* __restrict__ W,
                                           float (*tb)[H], int tid) {
    const int j = tid & 31, iset = tid >> 5;
    float acc[7];
    int rows[7];
#pragma unroll
    for (int r = 0; r < 7; r++) {
        acc[r] = 0.f;
        int i = iset + r * 8;
        rows[r] = (i >= M) ? (M - 1) : i;
    }
#pragma unroll 2
    for (int k4 = 0; k4 < KIN / 4; k4++) {
        const float w0 = W[(4 * k4 + 0) * H + j];
        const float w1 = W[(4 * k4 + 1) * H + j];
        const float w2 = W[(4 * k4 + 2) * H + j];
        const float w3 = W[(4 * k4 + 3) * H + j];
#pragma unroll
        for (int r = 0; r < 7; r++) {
            const float4 xv = *(const float4*)(hin + rows[r] * istride + 4 * k4);
            acc[r] += xv.x * w0 + xv.y * w1 + xv.z * w2 + xv.w * w3;
        }
    }
#pragma unroll
    for (int r = 0; r < 7; r++) {
        int i = iset + r * 8;
        if (i < M) tb[i][j] = acc[r];
    }
}

// aggregation + bias + tanh. Padded CSR: row extents are multiples of 4; one
// u32 load gives 4 packed u8 src ids, one b128 gives 4 norms, then 4
// INDEPENDENT tbuf reads -- 4x shorter dependent-LDS chain than scalar form.
__device__ __forceinline__ void gcn_agg(const float (*tbuf)[H], const float* __restrict__ b,
                                        float (*lat)[LATS], int col0,
                                        const float* dinv, const unsigned short* csr_off,
                                        const unsigned char* csr_src, const float* csr_nrm,
                                        int tid) {
    const int j = tid & 31, iset = tid >> 5;
    for (int i = iset; i < M; i += 8) {
        float acc = tbuf[i][j] * dinv[i] * dinv[i];   // self loop: norm = 1/deg
        int e0 = csr_off[i], e1 = csr_off[i + 1];
        for (int e = e0; e < e1; e += 4) {
            unsigned sp = *(const unsigned*)(csr_src + e);
            float4 nr = *(const float4*)(csr_nrm + e);
            acc += tbuf[sp & 255][j] * nr.x;
            acc += tbuf[(sp >> 8) & 255][j] * nr.y;
            acc += tbuf[(sp >> 16) & 255][j] * nr.z;
            acc += tbuf[sp >> 24][j] * nr.w;
        }
        lat[i][col0 + j] = fast_tanh(acc + b[j]);
    }
}

struct Post {                                      // 3392 B tail (phase union)
    float pbuf[16][15];
    union {
        struct { float z1[16][KTOP]; unsigned char ord[52]; } a;
        struct { float z2[352]; float red[256]; } b;
    } u;
};

// (256,4): spill-free point (64 VGPR, r2/r5/r8/r9). (256,5) clamps to 48
// VGPR + 70 MB scratch spill (r3); (256,3) changes nothing (r8).
__global__ __launch_bounds__(NTHREADS, 4)
void dgcnn_kernel(const float* __restrict__ x, const int* __restrict__ eidx,
                  const float* __restrict__ ws,
                  const float* __restrict__ W0, const float* __restrict__ b0,
                  const float* __restrict__ W1, const float* __restrict__ b1,
                  const float* __restrict__ W2, const float* __restrict__ b2,
                  const float* __restrict__ W3, const float* __restrict__ b3,
                  const float* __restrict__ C1b,
                  const float* __restrict__ C2w, const float* __restrict__ C2b,
                  const float* __restrict__ L1w, const float* __restrict__ L1b,
                  const float* __restrict__ L2w, const float* __restrict__ L2b,
                  float* __restrict__ out) {
    // xs (25600 B) is live only [stage .. layer-1 matmul]; lat+post born
    // after -> union. Total LDS 35264 B -> 4 blocks/CU (matches measured
    // occupancy of r5/r8/r9, so the union costs nothing).
    __shared__ __align__(16) union Big {
        float xs[M][F_IN];                 // 25600 B, dies after matmul-1
        struct { float lat[M][LATS]; Post post; } s;   // 23392 B
    } big;
    __shared__ __align__(16) float tbuf[M][H];     //  6400 B
    __shared__ __align__(16) float csr_nrm[PADE];  //  2208 B
    __shared__ unsigned char csr_src[PADE];        //   552 B
    __shared__ unsigned short csr_off[M + 2];      //   104 B
    __shared__ int   degi[M];                      //   200 B (becomes cursor)
    __shared__ float dinv[M];                      //   200 B

    const int g = blockIdx.x;
    const int tid = threadIdx.x;
    const int nbase = g * M;
    const int ebase = g * EPG;

    // ---- stage x tile -> LDS (coalesced float4); layer-1 then runs from
    // LDS broadcast instead of HBM-latency loads (r9: -41us).
    {
        const float4* xg4 = (const float4*)(x + (size_t)nbase * F_IN);
        float4* xs4 = (float4*)big.xs;
        for (int idx = tid; idx < M * F_IN / 4; idx += NTHREADS)
            xs4[idx] = xg4[idx];
    }
    // ---- init: degrees + zero padded CSR ----
    if (tid < M) degi[tid] = 1;
    for (int idx = tid; idx < PADE; idx += NTHREADS) {
        csr_nrm[idx] = 0.f;
        csr_src[idx] = 0;
    }
    __syncthreads();
    for (int e = tid; e < EPG; e += NTHREADS) {
        int d = eidx[E_TOTAL + ebase + e] - nbase;
        atomicAdd(&degi[d], 1);
    }
    __syncthreads();
    // ---- dinv + padded-CSR offsets (wave-0 shuffle scan); cursor=degi ----
    if (tid < M) dinv[tid] = rsqrtf((float)degi[tid]);
    if (tid < 64) {
        int cnt  = (tid < M) ? (degi[tid] - 1) : 0;
        int cntp = (cnt + 3) & ~3;
        int incl = cntp;
#pragma unroll
        for (int off = 1; off < 64; off <<= 1) {
            int nv = __shfl_up(incl, off);
            if (tid >= off) incl += nv;
        }
        if (tid < M) {
            csr_off[tid] = (unsigned short)(incl - cntp);
            degi[tid] = incl - cntp;
        }
        if (tid == M - 1) csr_off[M] = (unsigned short)incl;
    }
    __syncthreads();
    // ---- CSR fill + layer-1 matmul (independent; one barrier for both) ----
    for (int e = tid; e < EPG; e += NTHREADS) {
        int s = eidx[ebase + e] - nbase;
        int d = eidx[E_TOTAL + ebase + e] - nbase;
        float nr = dinv[s] * dinv[d];
        int pos = atomicAdd(&degi[d], 1);
        csr_src[pos] = (unsigned char)s;
        csr_nrm[pos] = nr;
    }
    gcn_matmul<F_IN>(&big.xs[0][0], F_IN, W0, tbuf, tid);
    __syncthreads();                     // xs dead from here; lat/post live

    // ---- layer 1 agg -> lat[:,0:32]; also zero lat pad cols 97..99 ----
    gcn_agg(tbuf, b0, big.s.lat, 0, dinv, csr_off, csr_src, csr_nrm, tid);
    for (int idx = tid; idx < 3 * M; idx += NTHREADS)
        big.s.lat[idx / 3][DLAT + idx % 3] = 0.f;   // conv1 reads 100 cols
    __syncthreads();
    // ---- layer 2 ----
    gcn_matmul<H>(&big.s.lat[0][0], LATS, W1, tbuf, tid);
    __syncthreads();
    gcn_agg(tbuf, b1, big.s.lat, 32, dinv, csr_off, csr_src, csr_nrm, tid);
    __syncthreads();
    // ---- layer 3 ----
    gcn_matmul<H>(&big.s.lat[0][32], LATS, W2, tbuf, tid);
    __syncthreads();
    gcn_agg(tbuf, b2, big.s.lat, 64, dinv, csr_off, csr_src, csr_nrm, tid);
    __syncthreads();
    // ---- layer 4 (H -> 1): exact tanhf (sort key) ----
    if (tid < M) {
        float acc = 0.f;
        for (int k = 0; k < H; k++) acc += big.s.lat[tid][64 + k] * W3[k];
        tbuf[tid][0] = acc;
    }
    __syncthreads();
    if (tid < M) {
        float acc = tbuf[tid][0] * dinv[tid] * dinv[tid];
        int e0 = csr_off[tid], e1 = csr_off[tid + 1];
        for (int e = e0; e < e1; e += 4) {
            unsigned sp = *(const unsigned*)(csr_src + e);
            float4 nr = *(const float4*)(csr_nrm + e);
            acc += tbuf[sp & 255][0] * nr.x + tbuf[(sp >> 8) & 255][0] * nr.y
                 + tbuf[(sp >> 16) & 255][0] * nr.z + tbuf[sp >> 24][0] * nr.w;
        }
        big.s.lat[tid][96] = tanhf(acc + b3[0]);
    }
    __syncthreads();

    // ---- sort-pool: stable descending rank over lat[:,96] ----
    if (tid < M) {
        float v = big.s.lat[tid][96];
        int r = 0;
        for (int jj = 0; jj < M; jj++) {
            float vj = big.s.lat[jj][96];
            r += (vj > v) || (vj == v && jj < tid);
        }
        big.s.post.u.a.ord[r] = (unsigned char)tid;
    }
    __syncthreads();

    // ---- Conv1d(1,16,97,stride 97) + ReLU, float4 over d ----
    // t=idx>>4: 16 lanes share a row -> LDS b128 broadcast; C1P rows (ws)
    // are 100 floats = 400 B (16B-aligned), pad cols = 0.
    for (int idx = tid; idx < 16 * KTOP; idx += NTHREADS) {
        int t = idx >> 4, c = idx & 15;
        const float4* row = (const float4*)big.s.lat[big.s.post.u.a.ord[t]];
        const float4* cw  = (const float4*)(ws + WS_C1P + c * LATS);
        float acc = 0.f;
#pragma unroll 5
        for (int q = 0; q < LATS / 4; q++) {
            float4 rv = row[q], wv = cw[q];
            acc += rv.x * wv.x + rv.y * wv.y + rv.z * wv.z + rv.w * wv.w;
        }
        big.s.post.u.a.z1[c][t] = fmaxf(acc + C1b[c], 0.f);
    }
    __syncthreads();

    // ---- MaxPool1d(2,2) -> pbuf (outside inner union) ----
    for (int idx = tid; idx < 16 * 15; idx += NTHREADS) {
        int c = idx / 15, t = idx - c * 15;
        big.s.post.pbuf[c][t] = fmaxf(big.s.post.u.a.z1[c][2 * t],
                                      big.s.post.u.a.z1[c][2 * t + 1]);
    }
    __syncthreads();

    // ---- Conv1d(16,32,5) + ReLU, flatten f = o*11 + t ----
    for (int idx = tid; idx < 352; idx += NTHREADS) {
        int o = idx / 11, t = idx - o * 11;
        float acc = C2b[o];
        for (int i = 0; i < 16; i++) {
#pragma unroll
            for (int k = 0; k < 5; k++)
                acc += big.s.post.pbuf[i][t + k] * C2w[(o * 16 + i) * 5 + k];
        }
        big.s.post.u.b.z2[idx] = fmaxf(acc, 0.f);
    }
    __syncthreads();

    // ---- Dense 352 -> 128 + ReLU (split over 2 halves; coalesced L1w) ----
    {
        int jj = tid & 127, half = tid >> 7;
        float acc = (half == 0) ? L1b[jj] : 0.f;
        int f0 = half * 176;
        for (int f = f0; f < f0 + 176; f++)
            acc += big.s.post.u.b.z2[f] * L1w[f * 128 + jj];
        big.s.post.u.b.red[tid] = acc;
    }
    __syncthreads();
    // ---- fuse ReLU + Dense 128 -> 1 ----
    if (tid < 128)
        big.s.post.u.b.red[tid] =
            fmaxf(big.s.post.u.b.red[tid] + big.s.post.u.b.red[tid + 128], 0.f)
            * L2w[tid];
    __syncthreads();
    if (tid < 64) {
        float v = big.s.post.u.b.red[tid] + big.s.post.u.b.red[tid + 64];
#pragma unroll
        for (int off = 32; off >= 1; off >>= 1)
            v += __shfl_down(v, off);
        if (tid == 0) out[g] = v + L2b[0];
    }
}

extern "C" void kernel_launch(void* const* d_in, const int* in_sizes, int n_in,
                              void* d_out, int out_size, void* d_ws, size_t ws_size,
                              hipStream_t stream) {
    const float* x    = (const float*)d_in[0];
    const int*   eidx = (const int*)d_in[1];
    // d_in[2] (batch) unused: graphs are contiguous equal-size blocks
    float* ws = (float*)d_ws;
    prep_kernel<<<7, 256, 0, stream>>>((const float*)d_in[11], ws);
    dgcnn_kernel<<<NG, NTHREADS, 0, stream>>>(
        x, eidx, ws,
        (const float*)d_in[3],  (const float*)d_in[4],
        (const float*)d_in[5],  (const float*)d_in[6],
        (const float*)d_in[7],  (const float*)d_in[8],
        (const float*)d_in[9],  (const float*)d_in[10],
        (const float*)d_in[12],
        (const float*)d_in[13], (const float*)d_in[14],
        (const float*)d_in[15], (const float*)d_in[16],
        (const float*)d_in[17], (const float*)d_in[18],
        (float*)d_out);
}